// Round 15
// baseline (677.612 us; speedup 1.0000x reference)
//
#include <hip/hip_runtime.h>
#include <hip/hip_bf16.h>
#include <cstdint>
#include <cstddef>

typedef __hip_bfloat16 bf16;

#define N_NODES  50000
#define N_EDGES  150000
#define E_TOT    (N_EDGES + N_NODES)   /* CSR positions: edges (dst-sorted), then self-loops */
#define N_TILES  ((E_TOT + 15) / 16)
#define N_GRAPHS 1024
#define IN_DIM   78
#define K1P      128                   /* IN_DIM padded to mult of 64 (BK) */
#define OUT_DIM  64
#define HEADS    10
#define HID      640
#define NEG_SLOPE 0.2f
#define SCB      ((N_NODES + 255) / 256)   /* 196 scan blocks */

static __device__ __forceinline__ float b2f(bf16 v){ return __bfloat162float(v); }
static __device__ __forceinline__ bf16  f2b(float v){ return __float2bfloat16(v); }

__device__ __forceinline__ int clampi(int v, int hi){ return v < 0 ? 0 : (v >= hi ? hi - 1 : v); }

__device__ __forceinline__ float bf2f_bits(short s){
  return __uint_as_float(((unsigned)(unsigned short)s) << 16);
}
__device__ __forceinline__ short f2bf_bits(float v){      // RNE (used where accuracy matters)
  unsigned u = __float_as_uint(v);
  return (short)((u + 0x7fffu + ((u >> 16) & 1u)) >> 16);
}
__device__ __forceinline__ short f2bf_trunc(float v){     // cheap truncation (logits path)
  return (short)(__float_as_uint(v) >> 16);
}

// ---------------------------------------------------------------- fills
__global__ __launch_bounds__(256) void fill_u32(unsigned* __restrict__ p, unsigned v, int n){
  int i = blockIdx.x * 256 + threadIdx.x;
  if (i < n) p[i] = v;
}

// ---------------------------------------------------------------- dtype prep
__global__ __launch_bounds__(256) void conv_x(const float* __restrict__ x, bf16* __restrict__ XB){
  int i = blockIdx.x * 256 + threadIdx.x;
  if (i >= N_NODES * K1P) return;
  int n = i / K1P, k = i - n * K1P;
  XB[i] = f2b(k < IN_DIM ? x[(size_t)n * IN_DIM + k] : 0.f);
}

// 2 weight matrices -> contiguous transposed bf16 (layer-1 pair, K padded; small)
__global__ __launch_bounds__(256) void conv_wT2(const float* __restrict__ W0,
                                                const float* __restrict__ W1,
                                                bf16* __restrict__ WT,
                                                int K, int N, int Kp){
  int i = blockIdx.x * 256 + threadIdx.x;
  const int per = N * Kp;
  if (i >= 2 * per) return;
  int m = i / per, r = i - m * per;
  const float* W = m == 0 ? W0 : W1;
  int n = r / Kp, k = r - n * Kp;
  WT[i] = f2b(k < K ? W[(size_t)k * N + n] : 0.f);
}

// tiled transpose: 3x (640x640 f32, row-major k x n) -> bf16 WT[m][n][k]
__global__ __launch_bounds__(256) void conv_wT3t(const float* __restrict__ W0,
                                                 const float* __restrict__ W1,
                                                 const float* __restrict__ W2,
                                                 bf16* __restrict__ WT){
  __shared__ float t[32][33];
  int m = blockIdx.z;
  const float* W = m == 0 ? W0 : (m == 1 ? W1 : W2);
  int n0 = blockIdx.x * 32, k0 = blockIdx.y * 32;
  int tx = threadIdx.x & 31, ty = threadIdx.x >> 5;   // 32 x 8
#pragma unroll
  for (int r = 0; r < 32; r += 8)
    t[ty + r][tx] = W[(size_t)(k0 + ty + r) * HID + n0 + tx];   // coalesced in n
  __syncthreads();
  bf16* O = WT + (size_t)m * HID * HID;
#pragma unroll
  for (int r = 0; r < 32; r += 8)
    O[(size_t)(n0 + ty + r) * HID + k0 + tx] = f2b(t[tx][ty + r]);  // coalesced in k
}

// att -> B-fragment-ordered matrix for 16x16x32 MFMA
__global__ __launch_bounds__(256) void conv_attP(const float* __restrict__ a, bf16* __restrict__ P,
                                                 int heads){
  int i = blockIdx.x * 256 + threadIdx.x;
  if (i >= (HID / 32) * 512) return;
  int chunk = i >> 9;
  int lane  = (i >> 3) & 63;
  int j     = i & 7;
  int h = lane & 15;
  int k = (lane >> 4) * 8 + j;
  int c = chunk * 32 + k;
  float v = 0.f;
  if (heads == HEADS){ if (h < HEADS && (c >> 6) == h) v = a[c]; }
  else               { if (h == 0) v = a[c]; }
  P[i] = f2b(v);
}

// ---------------------------------------------------------------- MFMA GEMM (BK=64)
#define BM 128
#define BN 128
#define BK 64

typedef __attribute__((ext_vector_type(8))) short bf16x8;
typedef __attribute__((ext_vector_type(4))) float f32x4;

typedef const __attribute__((address_space(1))) unsigned gu32;
typedef __attribute__((address_space(3))) unsigned lu32;

__global__ __launch_bounds__(256) void mfma_gemm(const bf16* __restrict__ A,
                                                 const bf16* __restrict__ BT,
                                                 bf16* __restrict__ C0,
                                                 bf16* __restrict__ C1,
                                                 int M, int Kp, int NB){
  // block swizzle: all NB col-tiles of a row strip stay on one XCD (d%8 = XCD round-robin)
  int d   = blockIdx.x;
  int xcd = d & 7, j = d >> 3;
  int cb  = j % NB, ri = j / NB;
  int rb  = ri * 8 + xcd;
  const int row0 = rb * BM;
  if (row0 >= M) return;
  const int col0 = cb * BN;

  // LDS slot (r, kc) holds source k-chunk kc ^ (r&7): full 32-bank coverage, 2-way (free)
  __shared__ short As[BM * BK];   // 16 KB
  __shared__ short Bs[BN * BK];   // 16 KB
  const int tid  = threadIdx.x;
  const int lane = tid & 63;
  const int wave = tid >> 6;
  const int wr   = (wave >> 1) * 64;
  const int wc   = (wave & 1) * 64;
  const int l15  = lane & 15;
  const int quad = lane >> 4;
  const int sw   = l15 & 7;       // row-XOR term (wr, i*16 are multiples of 8)

  const bf16* aptr[4];
  const bf16* bptr[4];
  lu32* lda[4];
  lu32* ldb[4];
#pragma unroll
  for (int t = 0; t < 4; ++t){
    int ci = (t * 4 + wave) * 64 + lane;
    int r  = ci >> 3;
    int sc = (ci & 7) ^ (r & 7);
    int gr = row0 + r; if (gr >= M) gr = M - 1;
    aptr[t] = A  + (size_t)gr * Kp + sc * 8;
    bptr[t] = BT + (size_t)(col0 + r) * Kp + sc * 8;
    lda[t]  = (lu32*)(&As[(t * 4 + wave) * 512]);
    ldb[t]  = (lu32*)(&Bs[(t * 4 + wave) * 512]);
  }

  f32x4 acc[4][4];
#pragma unroll
  for (int i = 0; i < 4; ++i)
#pragma unroll
    for (int jj = 0; jj < 4; ++jj) acc[i][jj] = (f32x4){0.f, 0.f, 0.f, 0.f};

  for (int k0 = 0; k0 < Kp; k0 += BK){
#pragma unroll
    for (int t = 0; t < 4; ++t){
      __builtin_amdgcn_global_load_lds((gu32*)(aptr[t] + k0), lda[t], 16, 0, 0);
      __builtin_amdgcn_global_load_lds((gu32*)(bptr[t] + k0), ldb[t], 16, 0, 0);
    }
    __syncthreads();

#pragma unroll
    for (int ks = 0; ks < 2; ++ks){
      const int slotA = ((ks * 4 + quad) ^ sw) * 8;
      bf16x8 af[4], bfr[4];
#pragma unroll
      for (int i = 0; i < 4; ++i)
        af[i] = *(bf16x8*)(&As[(wr + i * 16 + l15) * BK + slotA]);
#pragma unroll
      for (int jj = 0; jj < 4; ++jj)
        bfr[jj] = *(bf16x8*)(&Bs[(wc + jj * 16 + l15) * BK + slotA]);
#pragma unroll
      for (int i = 0; i < 4; ++i)
#pragma unroll
        for (int jj = 0; jj < 4; ++jj)
          acc[i][jj] = __builtin_amdgcn_mfma_f32_16x16x32_bf16(af[i], bfr[jj], acc[i][jj], 0, 0, 0);
    }
    __syncthreads();
  }

  // epilogue: C/D layout col=lane&15, row=quad*4+reg; column-split dual output
  if (row0 + BM <= M){          // full strip: no row guards (391/392 tiles)
#pragma unroll
    for (int i = 0; i < 4; ++i){
#pragma unroll
      for (int jj = 0; jj < 4; ++jj){
        int gc = col0 + wc + jj * 16 + l15;
        bf16* Cp = (gc < HID) ? C0 : C1;
        size_t cc = (gc < HID) ? gc : gc - HID;
        size_t base = (size_t)(row0 + wr + i * 16 + quad * 4) * HID + cc;
#pragma unroll
        for (int r = 0; r < 4; ++r)
          Cp[base + (size_t)r * HID] = f2b(acc[i][jj][r]);
      }
    }
  } else {
#pragma unroll
    for (int i = 0; i < 4; ++i){
#pragma unroll
      for (int jj = 0; jj < 4; ++jj){
        int gc = col0 + wc + jj * 16 + l15;
        bf16* Cp = (gc < HID) ? C0 : C1;
        int cc   = (gc < HID) ? gc : gc - HID;
#pragma unroll
        for (int r = 0; r < 4; ++r){
          int gr = row0 + wr + i * 16 + quad * 4 + r;
          if (gr < M) Cp[(size_t)gr * HID + cc] = f2b(acc[i][jj][r]);
        }
      }
    }
  }
}

// ---------------------------------------------------------------- CSR build
__global__ __launch_bounds__(256) void count_deg(const int* __restrict__ edst, int* __restrict__ degi){
  int e = blockIdx.x * 256 + threadIdx.x;
  if (e >= N_EDGES) return;
  atomicAdd(&degi[clampi(edst[e], N_NODES)], 1);
}

// phase 1: per-block exclusive scan; block sums to bsum; dinv computed here
__global__ __launch_bounds__(256) void scan_blk(const int* __restrict__ degi,
                                                int* __restrict__ rowp,
                                                float* __restrict__ dinv,
                                                int* __restrict__ bsum){
  __shared__ int wsum[4];
  int b = blockIdx.x, tid = threadIdx.x;
  int i = b * 256 + tid;
  int lane = tid & 63, wv = tid >> 6;
  int v = (i < N_NODES) ? degi[i] : 0;
  int incl = v;
#pragma unroll
  for (int ofs = 1; ofs < 64; ofs <<= 1){
    int t = __shfl_up(incl, ofs);
    if (lane >= ofs) incl += t;
  }
  if (lane == 63) wsum[wv] = incl;
  __syncthreads();
  int woff = 0;
#pragma unroll
  for (int w = 0; w < 4; ++w) if (w < wv) woff += wsum[w];
  if (i < N_NODES){
    rowp[i] = woff + incl - v;            // block-local exclusive
    dinv[i] = rsqrtf((float)(v + 1));
  }
  if (tid == 0) bsum[b] = wsum[0] + wsum[1] + wsum[2] + wsum[3];
}

// phase 2: single block scans bsum[SCB] exclusive in place; total -> rowp[N_NODES]
__global__ __launch_bounds__(256) void scan_top(int* __restrict__ bsum, int* __restrict__ rowp){
  __shared__ int wsum[4];
  int tid = threadIdx.x, lane = tid & 63, wv = tid >> 6;
  int v = (tid < SCB) ? bsum[tid] : 0;
  int incl = v;
#pragma unroll
  for (int ofs = 1; ofs < 64; ofs <<= 1){
    int t = __shfl_up(incl, ofs);
    if (lane >= ofs) incl += t;
  }
  if (lane == 63) wsum[wv] = incl;
  __syncthreads();
  int woff = 0;
#pragma unroll
  for (int w = 0; w < 4; ++w) if (w < wv) woff += wsum[w];
  if (tid < SCB) bsum[tid] = woff + incl - v;
  if (tid == 255) rowp[N_NODES] = woff + incl;   // grand total (v=0 past SCB)
}

// phase 3: add block offsets; curs = rowp
__global__ __launch_bounds__(256) void scan_add(const int* __restrict__ bsum,
                                                int* __restrict__ rowp,
                                                int* __restrict__ curs){
  int i = blockIdx.x * 256 + threadIdx.x;
  if (i >= N_NODES) return;
  int r = rowp[i] + bsum[blockIdx.x];
  rowp[i] = r; curs[i] = r;
}

__global__ __launch_bounds__(256) void bucket_edges(const int* __restrict__ esrc,
                                                    const int* __restrict__ edst,
                                                    int* __restrict__ curs,
                                                    int* __restrict__ srcg,
                                                    int* __restrict__ dstg){
  int e = blockIdx.x * 256 + threadIdx.x;
  if (e >= N_EDGES) return;
  int d = clampi(edst[e], N_NODES);
  int pos = atomicAdd(&curs[d], 1);
  srcg[pos] = clampi(esrc[e], N_NODES);
  dstg[pos] = d;
}

// ---------------------------------------------------------------- MFMA logits (CSR order, k-unrolled x2)
__global__ __launch_bounds__(256) void logits_mfma(const bf16* __restrict__ xl,
                                                   const bf16* __restrict__ xr,
                                                   const int* __restrict__ srcg,
                                                   const int* __restrict__ dstg,
                                                   const bf16* __restrict__ attP,
                                                   float* __restrict__ LOG,
                                                   int only0){
  int wid  = (blockIdx.x * 256 + threadIdx.x) >> 6;
  int lane = threadIdx.x & 63;
  if (wid >= N_TILES) return;
  const int l15 = lane & 15, quad = lane >> 4;
  int p = wid * 16 + l15; if (p >= E_TOT) p = E_TOT - 1;
  int s, d;
  if (p < N_EDGES){ s = srcg[p]; d = dstg[p]; }
  else            { s = d = p - N_EDGES; }
  const bf16* ps = xl + (size_t)s * HID + quad * 8;
  const bf16* pd = xr + (size_t)d * HID + quad * 8;
  const bf16* pw = attP + lane * 8;

  f32x4 acc = (f32x4){0.f, 0.f, 0.f, 0.f};
  for (int k0 = 0; k0 < HID; k0 += 64){       // 10 iterations, 4 gathers in flight
    bf16x8 va0 = *(const bf16x8*)(ps + k0);
    bf16x8 vb0 = *(const bf16x8*)(pd + k0);
    bf16x8 va1 = *(const bf16x8*)(ps + k0 + 32);
    bf16x8 vb1 = *(const bf16x8*)(pd + k0 + 32);
    bf16x8 t0, t1;
#pragma unroll
    for (int j = 0; j < 8; ++j){
      float v0 = bf2f_bits(va0[j]) + bf2f_bits(vb0[j]);
      v0 *= (v0 > 0.f) ? 1.f : NEG_SLOPE;
      t0[j] = f2bf_trunc(v0);
      float v1 = bf2f_bits(va1[j]) + bf2f_bits(vb1[j]);
      v1 *= (v1 > 0.f) ? 1.f : NEG_SLOPE;
      t1[j] = f2bf_trunc(v1);
    }
    bf16x8 wb0 = *(const bf16x8*)(pw + (k0 >> 5) * 512);
    bf16x8 wb1 = *(const bf16x8*)(pw + ((k0 >> 5) + 1) * 512);
    acc = __builtin_amdgcn_mfma_f32_16x16x32_bf16(t0, wb0, acc, 0, 0, 0);
    acc = __builtin_amdgcn_mfma_f32_16x16x32_bf16(t1, wb1, acc, 0, 0, 0);
  }
  int er = wid * 16 + quad * 4;
  if (only0){
    if (l15 == 0){
#pragma unroll
      for (int r = 0; r < 4; ++r){
        int ee = er + r;
        if (ee < E_TOT) LOG[ee] = acc[r];
      }
    }
  } else {
#pragma unroll
    for (int r = 0; r < 4; ++r){
      int ee = er + r;
      if (ee < E_TOT) LOG[(size_t)ee * 16 + l15] = acc[r];
    }
  }
}

// ---------------------------------------------------------------- GAT1 aggregation (2-way unrolled)
// lane l owns ch [8l,8l+8) (head l>>3) and ch {512+2l,513+2l} (head 8+(l>>5)).
__global__ __launch_bounds__(256) void gat1_agg(const bf16* __restrict__ xl,
                                                const int* __restrict__ srcg,
                                                const int* __restrict__ rowp,
                                                const float* __restrict__ LOG,
                                                const float* __restrict__ bias,
                                                bf16* __restrict__ H){
  int n    = (blockIdx.x * 256 + threadIdx.x) >> 6;
  int lane = threadIdx.x & 63;
  if (n >= N_NODES) return;
  const int l15 = lane & 15;
  const int hA = lane >> 3;
  const int hB = 8 + (lane >> 5);
  int r0 = rowp[n], r1 = rowp[n + 1];

  float lself = LOG[(size_t)(N_EDGES + n) * 16 + l15];
  float m = lself;
  for (int p = r0; p < r1; ++p) m = fmaxf(m, LOG[(size_t)p * 16 + l15]);

  float p0  = __expf(lself - m);
  float den = p0;
  float accA[8], accB[2];
  {
    float pA = __shfl(p0, hA), pB = __shfl(p0, hB);
    const bf16* xn = xl + (size_t)n * HID;
    bf16x8 va = *(const bf16x8*)(xn + 8 * lane);
    unsigned vb = *(const unsigned*)(xn + 512 + 2 * lane);
#pragma unroll
    for (int j = 0; j < 8; ++j) accA[j] = pA * bf2f_bits(va[j]);
    accB[0] = pB * bf2f_bits((short)(vb & 0xffff));
    accB[1] = pB * bf2f_bits((short)(vb >> 16));
  }
  int p = r0;
  for (; p + 1 < r1; p += 2){
    int s0 = srcg[p], s1 = srcg[p + 1];
    float l0 = LOG[(size_t)p * 16 + l15];
    float l1 = LOG[(size_t)(p + 1) * 16 + l15];
    const bf16* xs0 = xl + (size_t)s0 * HID;
    const bf16* xs1 = xl + (size_t)s1 * HID;
    bf16x8 va0 = *(const bf16x8*)(xs0 + 8 * lane);
    bf16x8 va1 = *(const bf16x8*)(xs1 + 8 * lane);
    unsigned vb0 = *(const unsigned*)(xs0 + 512 + 2 * lane);
    unsigned vb1 = *(const unsigned*)(xs1 + 512 + 2 * lane);
    float pv0 = __expf(l0 - m), pv1 = __expf(l1 - m);
    den += pv0 + pv1;
    float pA0 = __shfl(pv0, hA), pB0 = __shfl(pv0, hB);
    float pA1 = __shfl(pv1, hA), pB1 = __shfl(pv1, hB);
#pragma unroll
    for (int j = 0; j < 8; ++j) accA[j] += pA0 * bf2f_bits(va0[j]) + pA1 * bf2f_bits(va1[j]);
    accB[0] += pB0 * bf2f_bits((short)(vb0 & 0xffff)) + pB1 * bf2f_bits((short)(vb1 & 0xffff));
    accB[1] += pB0 * bf2f_bits((short)(vb0 >> 16))    + pB1 * bf2f_bits((short)(vb1 >> 16));
  }
  if (p < r1){
    int s = srcg[p];
    float pv = __expf(LOG[(size_t)p * 16 + l15] - m);
    den += pv;
    float pA = __shfl(pv, hA), pB = __shfl(pv, hB);
    const bf16* xs = xl + (size_t)s * HID;
    bf16x8 va = *(const bf16x8*)(xs + 8 * lane);
    unsigned vb = *(const unsigned*)(xs + 512 + 2 * lane);
#pragma unroll
    for (int j = 0; j < 8; ++j) accA[j] += pA * bf2f_bits(va[j]);
    accB[0] += pB * bf2f_bits((short)(vb & 0xffff));
    accB[1] += pB * bf2f_bits((short)(vb >> 16));
  }
  float dA = __shfl(den, hA), dB = __shfl(den, hB);
  float4 bA0 = *(const float4*)(bias + 8 * lane);
  float4 bA1 = *(const float4*)(bias + 8 * lane + 4);
  float2 bB  = *(const float2*)(bias + 512 + 2 * lane);
  bf16x8 oA;
  float bAa[8] = {bA0.x, bA0.y, bA0.z, bA0.w, bA1.x, bA1.y, bA1.z, bA1.w};
#pragma unroll
  for (int j = 0; j < 8; ++j){
    float v = accA[j] / dA + bAa[j];
    v = v > 0.f ? v : (__expf(v) - 1.f);              // ELU
    oA[j] = f2bf_bits(v);
  }
  float v0 = accB[0] / dB + bB.x; v0 = v0 > 0.f ? v0 : (__expf(v0) - 1.f);
  float v1 = accB[1] / dB + bB.y; v1 = v1 > 0.f ? v1 : (__expf(v1) - 1.f);
  bf16* hn = H + (size_t)n * HID;
  *(bf16x8*)(hn + 8 * lane) = oA;
  unsigned ob = (unsigned)(unsigned short)f2bf_bits(v0) |
                ((unsigned)(unsigned short)f2bf_bits(v1) << 16);
  *(unsigned*)(hn + 512 + 2 * lane) = ob;
}

// ---------------------------------------------------------------- GAT2 aggregation (1 head, compact LOG, unrolled)
__global__ __launch_bounds__(256) void gat2_agg(const bf16* __restrict__ xl,
                                                const int* __restrict__ srcg,
                                                const int* __restrict__ rowp,
                                                const float* __restrict__ LOG,
                                                const float* __restrict__ bias,
                                                bf16* __restrict__ H){
  int n    = (blockIdx.x * 256 + threadIdx.x) >> 6;
  int lane = threadIdx.x & 63;
  if (n >= N_NODES) return;
  int r0 = rowp[n], r1 = rowp[n + 1];

  float lself = LOG[N_EDGES + n];
  float m = lself;
  for (int p = r0; p < r1; ++p) m = fmaxf(m, LOG[p]);

  float p0  = __expf(lself - m);
  float den = p0;
  float accA[8], accB[2];
  {
    const bf16* xn = xl + (size_t)n * HID;
    bf16x8 va = *(const bf16x8*)(xn + 8 * lane);
    unsigned vb = *(const unsigned*)(xn + 512 + 2 * lane);
#pragma unroll
    for (int j = 0; j < 8; ++j) accA[j] = p0 * bf2f_bits(va[j]);
    accB[0] = p0 * bf2f_bits((short)(vb & 0xffff));
    accB[1] = p0 * bf2f_bits((short)(vb >> 16));
  }
  int p = r0;
  for (; p + 1 < r1; p += 2){
    int s0 = srcg[p], s1 = srcg[p + 1];
    float pv0 = __expf(LOG[p] - m), pv1 = __expf(LOG[p + 1] - m);
    const bf16* xs0 = xl + (size_t)s0 * HID;
    const bf16* xs1 = xl + (size_t)s1 * HID;
    bf16x8 va0 = *(const bf16x8*)(xs0 + 8 * lane);
    bf16x8 va1 = *(const bf16x8*)(xs1 + 8 * lane);
    unsigned vb0 = *(const unsigned*)(xs0 + 512 + 2 * lane);
    unsigned vb1 = *(const unsigned*)(xs1 + 512 + 2 * lane);
    den += pv0 + pv1;
#pragma unroll
    for (int j = 0; j < 8; ++j) accA[j] += pv0 * bf2f_bits(va0[j]) + pv1 * bf2f_bits(va1[j]);
    accB[0] += pv0 * bf2f_bits((short)(vb0 & 0xffff)) + pv1 * bf2f_bits((short)(vb1 & 0xffff));
    accB[1] += pv0 * bf2f_bits((short)(vb0 >> 16))    + pv1 * bf2f_bits((short)(vb1 >> 16));
  }
  if (p < r1){
    int s = srcg[p];
    float pv = __expf(LOG[p] - m);
    den += pv;
    const bf16* xs = xl + (size_t)s * HID;
    bf16x8 va = *(const bf16x8*)(xs + 8 * lane);
    unsigned vb = *(const unsigned*)(xs + 512 + 2 * lane);
#pragma unroll
    for (int j = 0; j < 8; ++j) accA[j] += pv * bf2f_bits(va[j]);
    accB[0] += pv * bf2f_bits((short)(vb & 0xffff));
    accB[1] += pv * bf2f_bits((short)(vb >> 16));
  }
  float inv = 1.f / den;
  float4 bA0 = *(const float4*)(bias + 8 * lane);
  float4 bA1 = *(const float4*)(bias + 8 * lane + 4);
  float2 bB  = *(const float2*)(bias + 512 + 2 * lane);
  float bAa[8] = {bA0.x, bA0.y, bA0.z, bA0.w, bA1.x, bA1.y, bA1.z, bA1.w};
  bf16x8 oA;
#pragma unroll
  for (int j = 0; j < 8; ++j) oA[j] = f2bf_bits(accA[j] * inv + bAa[j]);
  bf16* hn = H + (size_t)n * HID;
  *(bf16x8*)(hn + 8 * lane) = oA;
  unsigned ob = (unsigned)(unsigned short)f2bf_bits(accB[0] * inv + bB.x) |
                ((unsigned)(unsigned short)f2bf_bits(accB[1] * inv + bB.y) << 16);
  *(unsigned*)(hn + 512 + 2 * lane) = ob;
}

// ---------------------------------------------------------------- fused GCN + pooling
// one block per graph (batch sorted); thread = channel; h3 never materialized.
__global__ __launch_bounds__(640) void gcn_pool(const bf16* __restrict__ xw,
                                                const int* __restrict__ srcg,
                                                const int* __restrict__ rowp,
                                                const float* __restrict__ dinv,
                                                const float* __restrict__ bg,
                                                const int* __restrict__ gstart,
                                                float* __restrict__ out){
  int g = blockIdx.x;
  int c = threadIdx.x;              // 0..639
  int n0 = gstart[g], n1 = gstart[g + 1];
  float bc = bg[c];
  float mx = 0.f, sm = 0.f;         // ReLU output >= 0, so max init 0 is exact
  const short* xs = (const short*)xw;
  for (int n = n0; n < n1; ++n){
    int r0 = rowp[n], r1 = rowp[n + 1];
    float dn = dinv[n];
    float acc = dn * dn * bf2f_bits(xs[(size_t)n * HID + c]);   // self loop
    for (int p = r0; p < r1; ++p){
      int s = srcg[p];
      acc += dinv[s] * dn * bf2f_bits(xs[(size_t)s * HID + c]); // coalesced row read
    }
    float v = fmaxf(acc + bc, 0.f);
    mx = fmaxf(mx, v);
    sm += v;
  }
  float mean = (n1 > n0) ? sm / (float)(n1 - n0) : 0.f;
  out[(size_t)g * 2 * HID + c]       = mx;
  out[(size_t)g * 2 * HID + HID + c] = mean;
}

// ---------------------------------------------------------------- graph bounds (batch is sorted)
__global__ __launch_bounds__(256) void graph_bounds(const int* __restrict__ batch,
                                                    int* __restrict__ gstart){
  int n = blockIdx.x * 256 + threadIdx.x;
  if (n >= N_NODES) return;
  int b = clampi(batch[n], N_GRAPHS);
  if (n == 0){
    for (int g = 0; g <= b; ++g) gstart[g] = 0;
  } else {
    int bp = clampi(batch[n - 1], N_GRAPHS);
    for (int g = bp + 1; g <= b; ++g) gstart[g] = n;
  }
  if (n == N_NODES - 1){
    for (int g = b + 1; g <= N_GRAPHS; ++g) gstart[g] = N_NODES;
  }
}

// ---------------------------------------------------------------- launch
extern "C" void kernel_launch(void* const* d_in, const int* in_sizes, int n_in,
                              void* d_out, int out_size, void* d_ws, size_t ws_size,
                              hipStream_t stream){
  const float* x     = (const float*)d_in[0];
  const int*   ei    = (const int*)d_in[1];
  const int*   batch = (const int*)d_in[2];
  const float* Wl1 = (const float*)d_in[3];
  const float* Wr1 = (const float*)d_in[4];
  const float* a1  = (const float*)d_in[5];
  const float* b1  = (const float*)d_in[6];
  const float* Wl2 = (const float*)d_in[7];
  const float* Wr2 = (const float*)d_in[8];
  const float* a2  = (const float*)d_in[9];
  const float* b2  = (const float*)d_in[10];
  const float* Wg  = (const float*)d_in[11];
  const float* bg  = (const float*)d_in[12];
  const int* esrc = ei;
  const int* edst = ei + N_EDGES;

  // ---- workspace layout (~222 MB) ----
  char* ws = (char*)d_ws;
  size_t off = 0;
  auto take = [&](size_t bytes)->char*{
    char* p = ws + off; off = (off + bytes + 255) & ~(size_t)255; return p;
  };
  bf16*     X1   = (bf16*)    take((size_t)N_NODES * HID * 2);
  bf16*     X2   = (bf16*)    take((size_t)N_NODES * HID * 2);
  bf16*     H    = (bf16*)    take((size_t)N_NODES * HID * 2);
  bf16*     XB   = (bf16*)    take((size_t)N_NODES * K1P * 2);
  // WT1l|WT1r contiguous (one 1280xK1P matrix); WT2l|WT2r|WTg contiguous.
  bf16*     WT1l = (bf16*)    take((size_t)HID * K1P * 2);
  bf16*     WT1r = (bf16*)    take((size_t)HID * K1P * 2);
  bf16*     WT2l = (bf16*)    take((size_t)HID * HID * 2);
  bf16*     WT2r = (bf16*)    take((size_t)HID * HID * 2);
  bf16*     WTg  = (bf16*)    take((size_t)HID * HID * 2);
  bf16*     AT1P = (bf16*)    take((size_t)(HID / 32) * 512 * 2);
  bf16*     AT2P = (bf16*)    take((size_t)(HID / 32) * 512 * 2);
  float*    LOG  = (float*)   take((size_t)E_TOT * 16 * 4);
  int*      DEGI = (int*)     take((size_t)N_NODES * 4);
  int*      ROWP = (int*)     take((size_t)(N_NODES + 1) * 4);
  int*      CURS = (int*)     take((size_t)N_NODES * 4);
  int*      SRCG = (int*)     take((size_t)N_EDGES * 4);
  int*      DSTG = (int*)     take((size_t)N_EDGES * 4);
  float*    DINV = (float*)   take((size_t)N_NODES * 4);
  int*      GST  = (int*)     take((size_t)(N_GRAPHS + 1) * 4);
  int*      BSUM = (int*)     take((size_t)SCB * 4);

  dim3 blk(256);
  auto fill = [&](void* p, unsigned v, int n){
    fill_u32<<<dim3((n + 255) / 256), blk, 0, stream>>>((unsigned*)p, v, n);
  };
  const int MB8     = ((N_NODES + BM - 1) / BM + 7) / 8;   // row strips per XCD (49)
  const int nblocks = (N_NODES * 64 + 255) / 256;
  const int lblocks = (N_TILES * 64 + 255) / 256;
  const int reblk   = (N_EDGES + 255) / 256;
  const int apn     = (HID / 32) * 512;

  // ---- prep + CSR ----
  conv_x<<<(N_NODES * K1P + 255) / 256, blk, 0, stream>>>(x, XB);
  conv_wT2<<<(2 * HID * K1P + 255) / 256, blk, 0, stream>>>(Wl1, Wr1, WT1l, IN_DIM, HID, K1P);
  conv_wT3t<<<dim3(HID / 32, HID / 32, 3), blk, 0, stream>>>(Wl2, Wr2, Wg, WT2l);
  conv_attP<<<(apn + 255) / 256, blk, 0, stream>>>(a1, AT1P, HEADS);
  conv_attP<<<(apn + 255) / 256, blk, 0, stream>>>(a2, AT2P, 1);
  fill(DEGI, 0u, N_NODES);
  count_deg<<<reblk, blk, 0, stream>>>(edst, DEGI);
  scan_blk<<<dim3(SCB), blk, 0, stream>>>(DEGI, ROWP, DINV, BSUM);
  scan_top<<<dim3(1), blk, 0, stream>>>(BSUM, ROWP);
  scan_add<<<dim3(SCB), blk, 0, stream>>>(BSUM, ROWP, CURS);
  bucket_edges<<<reblk, blk, 0, stream>>>(esrc, edst, CURS, SRCG, DSTG);
  graph_bounds<<<(N_NODES + 255) / 256, blk, 0, stream>>>(batch, GST);

  // ---- GATv2 layer 1 (merged Wl|Wr GEMM, N=1280) ----
  mfma_gemm<<<dim3(8 * MB8 * 10), blk, 0, stream>>>(XB, WT1l, X1, X2, N_NODES, K1P, 10);
  logits_mfma<<<lblocks, blk, 0, stream>>>(X1, X2, SRCG, DSTG, AT1P, LOG, 0);
  gat1_agg<<<nblocks, blk, 0, stream>>>(X1, SRCG, ROWP, LOG, b1, H);

  // ---- GATv2 layer 2 (merged Wl|Wr GEMM, N=1280; compact logits) ----
  mfma_gemm<<<dim3(8 * MB8 * 10), blk, 0, stream>>>(H, WT2l, X1, X2, N_NODES, HID, 10);
  logits_mfma<<<lblocks, blk, 0, stream>>>(X1, X2, SRCG, DSTG, AT2P, LOG, 1);
  gat2_agg<<<nblocks, blk, 0, stream>>>(X1, SRCG, ROWP, LOG, b2, H);

  // ---- GCN GEMM + fused aggregation/pooling ----
  mfma_gemm<<<dim3(8 * MB8 * 5), blk, 0, stream>>>(H, WTg, X1, X1, N_NODES, HID, 5);
  gcn_pool<<<dim3(N_GRAPHS), dim3(640), 0, stream>>>(X1, SRCG, ROWP, DINV, bg, GST, (float*)d_out);
}

// Round 16
// 607.918 us; speedup vs baseline: 1.1146x; 1.1146x over previous
//
#include <hip/hip_runtime.h>
#include <hip/hip_bf16.h>
#include <cstdint>
#include <cstddef>

typedef __hip_bfloat16 bf16;

#define N_NODES  50000
#define N_EDGES  150000
#define E_TOT    (N_EDGES + N_NODES)   /* CSR positions: edges (dst-sorted), then self-loops */
#define N_TILES  ((E_TOT + 15) / 16)
#define N_GRAPHS 1024
#define IN_DIM   78
#define K1P      128                   /* IN_DIM padded to mult of 64 (BK) */
#define OUT_DIM  64
#define HEADS    10
#define HID      640
#define NEG_SLOPE 0.2f
#define SCB      ((N_NODES + 255) / 256)   /* 196 scan blocks */

static __device__ __forceinline__ float b2f(bf16 v){ return __bfloat162float(v); }
static __device__ __forceinline__ bf16  f2b(float v){ return __float2bfloat16(v); }

__device__ __forceinline__ int clampi(int v, int hi){ return v < 0 ? 0 : (v >= hi ? hi - 1 : v); }

__device__ __forceinline__ float bf2f_bits(short s){
  return __uint_as_float(((unsigned)(unsigned short)s) << 16);
}
__device__ __forceinline__ short f2bf_bits(float v){      // RNE (used where accuracy matters)
  unsigned u = __float_as_uint(v);
  return (short)((u + 0x7fffu + ((u >> 16) & 1u)) >> 16);
}
__device__ __forceinline__ short f2bf_trunc(float v){     // cheap truncation (logits path)
  return (short)(__float_as_uint(v) >> 16);
}

// ---------------------------------------------------------------- fills
__global__ __launch_bounds__(256) void fill_u32(unsigned* __restrict__ p, unsigned v, int n){
  int i = blockIdx.x * 256 + threadIdx.x;
  if (i < n) p[i] = v;
}

// ---------------------------------------------------------------- dtype prep
__global__ __launch_bounds__(256) void conv_x(const float* __restrict__ x, bf16* __restrict__ XB){
  int i = blockIdx.x * 256 + threadIdx.x;
  if (i >= N_NODES * K1P) return;
  int n = i / K1P, k = i - n * K1P;
  XB[i] = f2b(k < IN_DIM ? x[(size_t)n * IN_DIM + k] : 0.f);
}

// 2 weight matrices -> contiguous transposed bf16 (layer-1 pair, K padded; small)
__global__ __launch_bounds__(256) void conv_wT2(const float* __restrict__ W0,
                                                const float* __restrict__ W1,
                                                bf16* __restrict__ WT,
                                                int K, int N, int Kp){
  int i = blockIdx.x * 256 + threadIdx.x;
  const int per = N * Kp;
  if (i >= 2 * per) return;
  int m = i / per, r = i - m * per;
  const float* W = m == 0 ? W0 : W1;
  int n = r / Kp, k = r - n * Kp;
  WT[i] = f2b(k < K ? W[(size_t)k * N + n] : 0.f);
}

// tiled transpose: 3x (640x640 f32, row-major k x n) -> bf16 WT[m][n][k]
__global__ __launch_bounds__(256) void conv_wT3t(const float* __restrict__ W0,
                                                 const float* __restrict__ W1,
                                                 const float* __restrict__ W2,
                                                 bf16* __restrict__ WT){
  __shared__ float t[32][33];
  int m = blockIdx.z;
  const float* W = m == 0 ? W0 : (m == 1 ? W1 : W2);
  int n0 = blockIdx.x * 32, k0 = blockIdx.y * 32;
  int tx = threadIdx.x & 31, ty = threadIdx.x >> 5;   // 32 x 8
#pragma unroll
  for (int r = 0; r < 32; r += 8)
    t[ty + r][tx] = W[(size_t)(k0 + ty + r) * HID + n0 + tx];   // coalesced in n
  __syncthreads();
  bf16* O = WT + (size_t)m * HID * HID;
#pragma unroll
  for (int r = 0; r < 32; r += 8)
    O[(size_t)(n0 + ty + r) * HID + k0 + tx] = f2b(t[tx][ty + r]);  // coalesced in k
}

// att -> B-fragment-ordered matrix for 16x16x32 MFMA
__global__ __launch_bounds__(256) void conv_attP(const float* __restrict__ a, bf16* __restrict__ P,
                                                 int heads){
  int i = blockIdx.x * 256 + threadIdx.x;
  if (i >= (HID / 32) * 512) return;
  int chunk = i >> 9;
  int lane  = (i >> 3) & 63;
  int j     = i & 7;
  int h = lane & 15;
  int k = (lane >> 4) * 8 + j;
  int c = chunk * 32 + k;
  float v = 0.f;
  if (heads == HEADS){ if (h < HEADS && (c >> 6) == h) v = a[c]; }
  else               { if (h == 0) v = a[c]; }
  P[i] = f2b(v);
}

// ---------------------------------------------------------------- MFMA GEMM (BK=64)
#define BM 128
#define BN 128
#define BK 64

typedef __attribute__((ext_vector_type(8))) short bf16x8;
typedef __attribute__((ext_vector_type(4))) float f32x4;

typedef const __attribute__((address_space(1))) unsigned gu32;
typedef __attribute__((address_space(3))) unsigned lu32;

__global__ __launch_bounds__(256) void mfma_gemm(const bf16* __restrict__ A,
                                                 const bf16* __restrict__ BT,
                                                 bf16* __restrict__ C0,
                                                 bf16* __restrict__ C1,
                                                 int M, int Kp, int NB){
  // block swizzle: all NB col-tiles of a row strip stay on one XCD (d%8 = XCD round-robin)
  int d   = blockIdx.x;
  int xcd = d & 7, j = d >> 3;
  int cb  = j % NB, ri = j / NB;
  int rb  = ri * 8 + xcd;
  const int row0 = rb * BM;
  if (row0 >= M) return;
  const int col0 = cb * BN;

  // LDS slot (r, kc) holds source k-chunk kc ^ (r&7): full 32-bank coverage, 2-way (free)
  __shared__ short As[BM * BK];   // 16 KB
  __shared__ short Bs[BN * BK];   // 16 KB
  const int tid  = threadIdx.x;
  const int lane = tid & 63;
  const int wave = tid >> 6;
  const int wr   = (wave >> 1) * 64;
  const int wc   = (wave & 1) * 64;
  const int l15  = lane & 15;
  const int quad = lane >> 4;
  const int sw   = l15 & 7;       // row-XOR term (wr, i*16 are multiples of 8)

  const bf16* aptr[4];
  const bf16* bptr[4];
  lu32* lda[4];
  lu32* ldb[4];
#pragma unroll
  for (int t = 0; t < 4; ++t){
    int ci = (t * 4 + wave) * 64 + lane;
    int r  = ci >> 3;
    int sc = (ci & 7) ^ (r & 7);
    int gr = row0 + r; if (gr >= M) gr = M - 1;
    aptr[t] = A  + (size_t)gr * Kp + sc * 8;
    bptr[t] = BT + (size_t)(col0 + r) * Kp + sc * 8;
    lda[t]  = (lu32*)(&As[(t * 4 + wave) * 512]);
    ldb[t]  = (lu32*)(&Bs[(t * 4 + wave) * 512]);
  }

  f32x4 acc[4][4];
#pragma unroll
  for (int i = 0; i < 4; ++i)
#pragma unroll
    for (int jj = 0; jj < 4; ++jj) acc[i][jj] = (f32x4){0.f, 0.f, 0.f, 0.f};

  for (int k0 = 0; k0 < Kp; k0 += BK){
#pragma unroll
    for (int t = 0; t < 4; ++t){
      __builtin_amdgcn_global_load_lds((gu32*)(aptr[t] + k0), lda[t], 16, 0, 0);
      __builtin_amdgcn_global_load_lds((gu32*)(bptr[t] + k0), ldb[t], 16, 0, 0);
    }
    __syncthreads();

#pragma unroll
    for (int ks = 0; ks < 2; ++ks){
      const int slotA = ((ks * 4 + quad) ^ sw) * 8;
      bf16x8 af[4], bfr[4];
#pragma unroll
      for (int i = 0; i < 4; ++i)
        af[i] = *(bf16x8*)(&As[(wr + i * 16 + l15) * BK + slotA]);
#pragma unroll
      for (int jj = 0; jj < 4; ++jj)
        bfr[jj] = *(bf16x8*)(&Bs[(wc + jj * 16 + l15) * BK + slotA]);
#pragma unroll
      for (int i = 0; i < 4; ++i)
#pragma unroll
        for (int jj = 0; jj < 4; ++jj)
          acc[i][jj] = __builtin_amdgcn_mfma_f32_16x16x32_bf16(af[i], bfr[jj], acc[i][jj], 0, 0, 0);
    }
    __syncthreads();
  }

  // epilogue: C/D layout col=lane&15, row=quad*4+reg; column-split dual output
  if (row0 + BM <= M){          // full strip: no row guards (391/392 tiles)
#pragma unroll
    for (int i = 0; i < 4; ++i){
#pragma unroll
      for (int jj = 0; jj < 4; ++jj){
        int gc = col0 + wc + jj * 16 + l15;
        bf16* Cp = (gc < HID) ? C0 : C1;
        size_t cc = (gc < HID) ? gc : gc - HID;
        size_t base = (size_t)(row0 + wr + i * 16 + quad * 4) * HID + cc;
#pragma unroll
        for (int r = 0; r < 4; ++r)
          Cp[base + (size_t)r * HID] = f2b(acc[i][jj][r]);
      }
    }
  } else {
#pragma unroll
    for (int i = 0; i < 4; ++i){
#pragma unroll
      for (int jj = 0; jj < 4; ++jj){
        int gc = col0 + wc + jj * 16 + l15;
        bf16* Cp = (gc < HID) ? C0 : C1;
        int cc   = (gc < HID) ? gc : gc - HID;
#pragma unroll
        for (int r = 0; r < 4; ++r){
          int gr = row0 + wr + i * 16 + quad * 4 + r;
          if (gr < M) Cp[(size_t)gr * HID + cc] = f2b(acc[i][jj][r]);
        }
      }
    }
  }
}

// ---------------------------------------------------------------- CSR build
__global__ __launch_bounds__(256) void count_deg(const int* __restrict__ edst, int* __restrict__ degi){
  int e = blockIdx.x * 256 + threadIdx.x;
  if (e >= N_EDGES) return;
  atomicAdd(&degi[clampi(edst[e], N_NODES)], 1);
}

// phase 1: per-block exclusive scan; block sums to bsum; dinv computed here
__global__ __launch_bounds__(256) void scan_blk(const int* __restrict__ degi,
                                                int* __restrict__ rowp,
                                                float* __restrict__ dinv,
                                                int* __restrict__ bsum){
  __shared__ int wsum[4];
  int b = blockIdx.x, tid = threadIdx.x;
  int i = b * 256 + tid;
  int lane = tid & 63, wv = tid >> 6;
  int v = (i < N_NODES) ? degi[i] : 0;
  int incl = v;
#pragma unroll
  for (int ofs = 1; ofs < 64; ofs <<= 1){
    int t = __shfl_up(incl, ofs);
    if (lane >= ofs) incl += t;
  }
  if (lane == 63) wsum[wv] = incl;
  __syncthreads();
  int woff = 0;
#pragma unroll
  for (int w = 0; w < 4; ++w) if (w < wv) woff += wsum[w];
  if (i < N_NODES){
    rowp[i] = woff + incl - v;            // block-local exclusive
    dinv[i] = rsqrtf((float)(v + 1));
  }
  if (tid == 0) bsum[b] = wsum[0] + wsum[1] + wsum[2] + wsum[3];
}

// phase 2: single block scans bsum[SCB] exclusive in place; total -> rowp[N_NODES]
__global__ __launch_bounds__(256) void scan_top(int* __restrict__ bsum, int* __restrict__ rowp){
  __shared__ int wsum[4];
  int tid = threadIdx.x, lane = tid & 63, wv = tid >> 6;
  int v = (tid < SCB) ? bsum[tid] : 0;
  int incl = v;
#pragma unroll
  for (int ofs = 1; ofs < 64; ofs <<= 1){
    int t = __shfl_up(incl, ofs);
    if (lane >= ofs) incl += t;
  }
  if (lane == 63) wsum[wv] = incl;
  __syncthreads();
  int woff = 0;
#pragma unroll
  for (int w = 0; w < 4; ++w) if (w < wv) woff += wsum[w];
  if (tid < SCB) bsum[tid] = woff + incl - v;
  if (tid == 255) rowp[N_NODES] = woff + incl;   // grand total (v=0 past SCB)
}

// phase 3: add block offsets; curs = rowp
__global__ __launch_bounds__(256) void scan_add(const int* __restrict__ bsum,
                                                int* __restrict__ rowp,
                                                int* __restrict__ curs){
  int i = blockIdx.x * 256 + threadIdx.x;
  if (i >= N_NODES) return;
  int r = rowp[i] + bsum[blockIdx.x];
  rowp[i] = r; curs[i] = r;
}

__global__ __launch_bounds__(256) void bucket_edges(const int* __restrict__ esrc,
                                                    const int* __restrict__ edst,
                                                    int* __restrict__ curs,
                                                    int* __restrict__ srcg,
                                                    int* __restrict__ dstg){
  int e = blockIdx.x * 256 + threadIdx.x;
  if (e >= N_EDGES) return;
  int d = clampi(edst[e], N_NODES);
  int pos = atomicAdd(&curs[d], 1);
  srcg[pos] = clampi(esrc[e], N_NODES);
  dstg[pos] = d;
}

// ---------------------------------------------------------------- MFMA logits (CSR order, k-unrolled x2)
__global__ __launch_bounds__(256) void logits_mfma(const bf16* __restrict__ xl,
                                                   const bf16* __restrict__ xr,
                                                   const int* __restrict__ srcg,
                                                   const int* __restrict__ dstg,
                                                   const bf16* __restrict__ attP,
                                                   float* __restrict__ LOG,
                                                   int only0){
  int wid  = (blockIdx.x * 256 + threadIdx.x) >> 6;
  int lane = threadIdx.x & 63;
  if (wid >= N_TILES) return;
  const int l15 = lane & 15, quad = lane >> 4;
  int p = wid * 16 + l15; if (p >= E_TOT) p = E_TOT - 1;
  int s, d;
  if (p < N_EDGES){ s = srcg[p]; d = dstg[p]; }
  else            { s = d = p - N_EDGES; }
  const bf16* ps = xl + (size_t)s * HID + quad * 8;
  const bf16* pd = xr + (size_t)d * HID + quad * 8;
  const bf16* pw = attP + lane * 8;

  f32x4 acc = (f32x4){0.f, 0.f, 0.f, 0.f};
  for (int k0 = 0; k0 < HID; k0 += 64){       // 10 iterations, 4 gathers in flight
    bf16x8 va0 = *(const bf16x8*)(ps + k0);
    bf16x8 vb0 = *(const bf16x8*)(pd + k0);
    bf16x8 va1 = *(const bf16x8*)(ps + k0 + 32);
    bf16x8 vb1 = *(const bf16x8*)(pd + k0 + 32);
    bf16x8 t0, t1;
#pragma unroll
    for (int j = 0; j < 8; ++j){
      float v0 = bf2f_bits(va0[j]) + bf2f_bits(vb0[j]);
      v0 *= (v0 > 0.f) ? 1.f : NEG_SLOPE;
      t0[j] = f2bf_trunc(v0);
      float v1 = bf2f_bits(va1[j]) + bf2f_bits(vb1[j]);
      v1 *= (v1 > 0.f) ? 1.f : NEG_SLOPE;
      t1[j] = f2bf_trunc(v1);
    }
    bf16x8 wb0 = *(const bf16x8*)(pw + (k0 >> 5) * 512);
    bf16x8 wb1 = *(const bf16x8*)(pw + ((k0 >> 5) + 1) * 512);
    acc = __builtin_amdgcn_mfma_f32_16x16x32_bf16(t0, wb0, acc, 0, 0, 0);
    acc = __builtin_amdgcn_mfma_f32_16x16x32_bf16(t1, wb1, acc, 0, 0, 0);
  }
  int er = wid * 16 + quad * 4;
  if (only0){
    if (l15 == 0){
#pragma unroll
      for (int r = 0; r < 4; ++r){
        int ee = er + r;
        if (ee < E_TOT) LOG[ee] = acc[r];
      }
    }
  } else {
#pragma unroll
    for (int r = 0; r < 4; ++r){
      int ee = er + r;
      if (ee < E_TOT) LOG[(size_t)ee * 16 + l15] = acc[r];
    }
  }
}

// ---------------------------------------------------------------- GAT1 aggregation (2-way unrolled)
// lane l owns ch [8l,8l+8) (head l>>3) and ch {512+2l,513+2l} (head 8+(l>>5)).
__global__ __launch_bounds__(256) void gat1_agg(const bf16* __restrict__ xl,
                                                const int* __restrict__ srcg,
                                                const int* __restrict__ rowp,
                                                const float* __restrict__ LOG,
                                                const float* __restrict__ bias,
                                                bf16* __restrict__ H){
  int n    = (blockIdx.x * 256 + threadIdx.x) >> 6;
  int lane = threadIdx.x & 63;
  if (n >= N_NODES) return;
  const int l15 = lane & 15;
  const int hA = lane >> 3;
  const int hB = 8 + (lane >> 5);
  int r0 = rowp[n], r1 = rowp[n + 1];

  float lself = LOG[(size_t)(N_EDGES + n) * 16 + l15];
  float m = lself;
  for (int p = r0; p < r1; ++p) m = fmaxf(m, LOG[(size_t)p * 16 + l15]);

  float p0  = __expf(lself - m);
  float den = p0;
  float accA[8], accB[2];
  {
    float pA = __shfl(p0, hA), pB = __shfl(p0, hB);
    const bf16* xn = xl + (size_t)n * HID;
    bf16x8 va = *(const bf16x8*)(xn + 8 * lane);
    unsigned vb = *(const unsigned*)(xn + 512 + 2 * lane);
#pragma unroll
    for (int j = 0; j < 8; ++j) accA[j] = pA * bf2f_bits(va[j]);
    accB[0] = pB * bf2f_bits((short)(vb & 0xffff));
    accB[1] = pB * bf2f_bits((short)(vb >> 16));
  }
  int p = r0;
  for (; p + 1 < r1; p += 2){
    int s0 = srcg[p], s1 = srcg[p + 1];
    float l0 = LOG[(size_t)p * 16 + l15];
    float l1 = LOG[(size_t)(p + 1) * 16 + l15];
    const bf16* xs0 = xl + (size_t)s0 * HID;
    const bf16* xs1 = xl + (size_t)s1 * HID;
    bf16x8 va0 = *(const bf16x8*)(xs0 + 8 * lane);
    bf16x8 va1 = *(const bf16x8*)(xs1 + 8 * lane);
    unsigned vb0 = *(const unsigned*)(xs0 + 512 + 2 * lane);
    unsigned vb1 = *(const unsigned*)(xs1 + 512 + 2 * lane);
    float pv0 = __expf(l0 - m), pv1 = __expf(l1 - m);
    den += pv0 + pv1;
    float pA0 = __shfl(pv0, hA), pB0 = __shfl(pv0, hB);
    float pA1 = __shfl(pv1, hA), pB1 = __shfl(pv1, hB);
#pragma unroll
    for (int j = 0; j < 8; ++j) accA[j] += pA0 * bf2f_bits(va0[j]) + pA1 * bf2f_bits(va1[j]);
    accB[0] += pB0 * bf2f_bits((short)(vb0 & 0xffff)) + pB1 * bf2f_bits((short)(vb1 & 0xffff));
    accB[1] += pB0 * bf2f_bits((short)(vb0 >> 16))    + pB1 * bf2f_bits((short)(vb1 >> 16));
  }
  if (p < r1){
    int s = srcg[p];
    float pv = __expf(LOG[(size_t)p * 16 + l15] - m);
    den += pv;
    float pA = __shfl(pv, hA), pB = __shfl(pv, hB);
    const bf16* xs = xl + (size_t)s * HID;
    bf16x8 va = *(const bf16x8*)(xs + 8 * lane);
    unsigned vb = *(const unsigned*)(xs + 512 + 2 * lane);
#pragma unroll
    for (int j = 0; j < 8; ++j) accA[j] += pA * bf2f_bits(va[j]);
    accB[0] += pB * bf2f_bits((short)(vb & 0xffff));
    accB[1] += pB * bf2f_bits((short)(vb >> 16));
  }
  float dA = __shfl(den, hA), dB = __shfl(den, hB);
  float4 bA0 = *(const float4*)(bias + 8 * lane);
  float4 bA1 = *(const float4*)(bias + 8 * lane + 4);
  float2 bB  = *(const float2*)(bias + 512 + 2 * lane);
  bf16x8 oA;
  float bAa[8] = {bA0.x, bA0.y, bA0.z, bA0.w, bA1.x, bA1.y, bA1.z, bA1.w};
#pragma unroll
  for (int j = 0; j < 8; ++j){
    float v = accA[j] / dA + bAa[j];
    v = v > 0.f ? v : (__expf(v) - 1.f);              // ELU
    oA[j] = f2bf_bits(v);
  }
  float v0 = accB[0] / dB + bB.x; v0 = v0 > 0.f ? v0 : (__expf(v0) - 1.f);
  float v1 = accB[1] / dB + bB.y; v1 = v1 > 0.f ? v1 : (__expf(v1) - 1.f);
  bf16* hn = H + (size_t)n * HID;
  *(bf16x8*)(hn + 8 * lane) = oA;
  unsigned ob = (unsigned)(unsigned short)f2bf_bits(v0) |
                ((unsigned)(unsigned short)f2bf_bits(v1) << 16);
  *(unsigned*)(hn + 512 + 2 * lane) = ob;
}

// ---------------------------------------------------------------- GAT2 aggregation (1 head, compact LOG, unrolled)
__global__ __launch_bounds__(256) void gat2_agg(const bf16* __restrict__ xl,
                                                const int* __restrict__ srcg,
                                                const int* __restrict__ rowp,
                                                const float* __restrict__ LOG,
                                                const float* __restrict__ bias,
                                                bf16* __restrict__ H){
  int n    = (blockIdx.x * 256 + threadIdx.x) >> 6;
  int lane = threadIdx.x & 63;
  if (n >= N_NODES) return;
  int r0 = rowp[n], r1 = rowp[n + 1];

  float lself = LOG[N_EDGES + n];
  float m = lself;
  for (int p = r0; p < r1; ++p) m = fmaxf(m, LOG[p]);

  float p0  = __expf(lself - m);
  float den = p0;
  float accA[8], accB[2];
  {
    const bf16* xn = xl + (size_t)n * HID;
    bf16x8 va = *(const bf16x8*)(xn + 8 * lane);
    unsigned vb = *(const unsigned*)(xn + 512 + 2 * lane);
#pragma unroll
    for (int j = 0; j < 8; ++j) accA[j] = p0 * bf2f_bits(va[j]);
    accB[0] = p0 * bf2f_bits((short)(vb & 0xffff));
    accB[1] = p0 * bf2f_bits((short)(vb >> 16));
  }
  int p = r0;
  for (; p + 1 < r1; p += 2){
    int s0 = srcg[p], s1 = srcg[p + 1];
    float pv0 = __expf(LOG[p] - m), pv1 = __expf(LOG[p + 1] - m);
    const bf16* xs0 = xl + (size_t)s0 * HID;
    const bf16* xs1 = xl + (size_t)s1 * HID;
    bf16x8 va0 = *(const bf16x8*)(xs0 + 8 * lane);
    bf16x8 va1 = *(const bf16x8*)(xs1 + 8 * lane);
    unsigned vb0 = *(const unsigned*)(xs0 + 512 + 2 * lane);
    unsigned vb1 = *(const unsigned*)(xs1 + 512 + 2 * lane);
    den += pv0 + pv1;
#pragma unroll
    for (int j = 0; j < 8; ++j) accA[j] += pv0 * bf2f_bits(va0[j]) + pv1 * bf2f_bits(va1[j]);
    accB[0] += pv0 * bf2f_bits((short)(vb0 & 0xffff)) + pv1 * bf2f_bits((short)(vb1 & 0xffff));
    accB[1] += pv0 * bf2f_bits((short)(vb0 >> 16))    + pv1 * bf2f_bits((short)(vb1 >> 16));
  }
  if (p < r1){
    int s = srcg[p];
    float pv = __expf(LOG[p] - m);
    den += pv;
    const bf16* xs = xl + (size_t)s * HID;
    bf16x8 va = *(const bf16x8*)(xs + 8 * lane);
    unsigned vb = *(const unsigned*)(xs + 512 + 2 * lane);
#pragma unroll
    for (int j = 0; j < 8; ++j) accA[j] += pv * bf2f_bits(va[j]);
    accB[0] += pv * bf2f_bits((short)(vb & 0xffff));
    accB[1] += pv * bf2f_bits((short)(vb >> 16));
  }
  float inv = 1.f / den;
  float4 bA0 = *(const float4*)(bias + 8 * lane);
  float4 bA1 = *(const float4*)(bias + 8 * lane + 4);
  float2 bB  = *(const float2*)(bias + 512 + 2 * lane);
  float bAa[8] = {bA0.x, bA0.y, bA0.z, bA0.w, bA1.x, bA1.y, bA1.z, bA1.w};
  bf16x8 oA;
#pragma unroll
  for (int j = 0; j < 8; ++j) oA[j] = f2bf_bits(accA[j] * inv + bAa[j]);
  bf16* hn = H + (size_t)n * HID;
  *(bf16x8*)(hn + 8 * lane) = oA;
  unsigned ob = (unsigned)(unsigned short)f2bf_bits(accB[0] * inv + bB.x) |
                ((unsigned)(unsigned short)f2bf_bits(accB[1] * inv + bB.y) << 16);
  *(unsigned*)(hn + 512 + 2 * lane) = ob;
}

// ---------------------------------------------------------------- GCN gather: bias+ReLU -> bf16 h3 (unrolled)
__global__ __launch_bounds__(256) void gcn_gather(const bf16* __restrict__ xw,
                                                  const int* __restrict__ srcg,
                                                  const int* __restrict__ rowp,
                                                  const float* __restrict__ dinv,
                                                  const float* __restrict__ bg,
                                                  bf16* __restrict__ h3){
  int n    = (blockIdx.x * 256 + threadIdx.x) >> 6;
  int lane = threadIdx.x & 63;
  if (n >= N_NODES) return;
  int r0 = rowp[n], r1 = rowp[n + 1];

  float dn = dinv[n];
  float accA[8], accB[2];
  {
    float w = dn * dn;
    const bf16* xn = xw + (size_t)n * HID;
    bf16x8 va = *(const bf16x8*)(xn + 8 * lane);
    unsigned vb = *(const unsigned*)(xn + 512 + 2 * lane);
#pragma unroll
    for (int j = 0; j < 8; ++j) accA[j] = w * bf2f_bits(va[j]);
    accB[0] = w * bf2f_bits((short)(vb & 0xffff));
    accB[1] = w * bf2f_bits((short)(vb >> 16));
  }
  int p = r0;
  for (; p + 1 < r1; p += 2){
    int s0 = srcg[p], s1 = srcg[p + 1];
    float w0 = dinv[s0] * dn, w1 = dinv[s1] * dn;
    const bf16* xs0 = xw + (size_t)s0 * HID;
    const bf16* xs1 = xw + (size_t)s1 * HID;
    bf16x8 va0 = *(const bf16x8*)(xs0 + 8 * lane);
    bf16x8 va1 = *(const bf16x8*)(xs1 + 8 * lane);
    unsigned vb0 = *(const unsigned*)(xs0 + 512 + 2 * lane);
    unsigned vb1 = *(const unsigned*)(xs1 + 512 + 2 * lane);
#pragma unroll
    for (int j = 0; j < 8; ++j) accA[j] += w0 * bf2f_bits(va0[j]) + w1 * bf2f_bits(va1[j]);
    accB[0] += w0 * bf2f_bits((short)(vb0 & 0xffff)) + w1 * bf2f_bits((short)(vb1 & 0xffff));
    accB[1] += w0 * bf2f_bits((short)(vb0 >> 16))    + w1 * bf2f_bits((short)(vb1 >> 16));
  }
  if (p < r1){
    int s = srcg[p];
    float w = dinv[s] * dn;
    const bf16* xs = xw + (size_t)s * HID;
    bf16x8 va = *(const bf16x8*)(xs + 8 * lane);
    unsigned vb = *(const unsigned*)(xs + 512 + 2 * lane);
#pragma unroll
    for (int j = 0; j < 8; ++j) accA[j] += w * bf2f_bits(va[j]);
    accB[0] += w * bf2f_bits((short)(vb & 0xffff));
    accB[1] += w * bf2f_bits((short)(vb >> 16));
  }
  float4 bA0 = *(const float4*)(bg + 8 * lane);
  float4 bA1 = *(const float4*)(bg + 8 * lane + 4);
  float2 bB  = *(const float2*)(bg + 512 + 2 * lane);
  float bAa[8] = {bA0.x, bA0.y, bA0.z, bA0.w, bA1.x, bA1.y, bA1.z, bA1.w};
  bf16x8 oA;
#pragma unroll
  for (int j = 0; j < 8; ++j) oA[j] = f2bf_bits(fmaxf(accA[j] + bAa[j], 0.f));
  bf16* hn = h3 + (size_t)n * HID;
  *(bf16x8*)(hn + 8 * lane) = oA;
  unsigned ob = (unsigned)(unsigned short)f2bf_bits(fmaxf(accB[0] + bB.x, 0.f)) |
                ((unsigned)(unsigned short)f2bf_bits(fmaxf(accB[1] + bB.y, 0.f)) << 16);
  *(unsigned*)(hn + 512 + 2 * lane) = ob;
}

// ---------------------------------------------------------------- per-graph pooling (batch is sorted)
__global__ __launch_bounds__(256) void graph_bounds(const int* __restrict__ batch,
                                                    int* __restrict__ gstart){
  int n = blockIdx.x * 256 + threadIdx.x;
  if (n >= N_NODES) return;
  int b = clampi(batch[n], N_GRAPHS);
  if (n == 0){
    for (int g = 0; g <= b; ++g) gstart[g] = 0;
  } else {
    int bp = clampi(batch[n - 1], N_GRAPHS);
    for (int g = bp + 1; g <= b; ++g) gstart[g] = n;
  }
  if (n == N_NODES - 1){
    for (int g = b + 1; g <= N_GRAPHS; ++g) gstart[g] = N_NODES;
  }
}

__global__ __launch_bounds__(640) void pool_graph(const bf16* __restrict__ h3,
                                                  const int* __restrict__ gstart,
                                                  float* __restrict__ out){
  int g = blockIdx.x;
  int c = threadIdx.x;
  int n0 = gstart[g], n1 = gstart[g + 1];
  float mx = 0.f, sm = 0.f;     // h3 >= 0 post-ReLU
  for (int n = n0; n < n1; ++n){
    float v = b2f(h3[(size_t)n * HID + c]);
    mx = fmaxf(mx, v); sm += v;
  }
  float mean = (n1 > n0) ? sm / (float)(n1 - n0) : 0.f;
  out[(size_t)g * 2 * HID + c]       = mx;
  out[(size_t)g * 2 * HID + HID + c] = mean;
}

// ---------------------------------------------------------------- launch
extern "C" void kernel_launch(void* const* d_in, const int* in_sizes, int n_in,
                              void* d_out, int out_size, void* d_ws, size_t ws_size,
                              hipStream_t stream){
  const float* x     = (const float*)d_in[0];
  const int*   ei    = (const int*)d_in[1];
  const int*   batch = (const int*)d_in[2];
  const float* Wl1 = (const float*)d_in[3];
  const float* Wr1 = (const float*)d_in[4];
  const float* a1  = (const float*)d_in[5];
  const float* b1  = (const float*)d_in[6];
  const float* Wl2 = (const float*)d_in[7];
  const float* Wr2 = (const float*)d_in[8];
  const float* a2  = (const float*)d_in[9];
  const float* b2  = (const float*)d_in[10];
  const float* Wg  = (const float*)d_in[11];
  const float* bg  = (const float*)d_in[12];
  const int* esrc = ei;
  const int* edst = ei + N_EDGES;

  // ---- workspace layout (~222 MB) ----
  char* ws = (char*)d_ws;
  size_t off = 0;
  auto take = [&](size_t bytes)->char*{
    char* p = ws + off; off = (off + bytes + 255) & ~(size_t)255; return p;
  };
  bf16*     X1   = (bf16*)    take((size_t)N_NODES * HID * 2);
  bf16*     X2   = (bf16*)    take((size_t)N_NODES * HID * 2);
  bf16*     H    = (bf16*)    take((size_t)N_NODES * HID * 2);
  bf16*     XB   = (bf16*)    take((size_t)N_NODES * K1P * 2);
  // WT1l|WT1r contiguous (one 1280xK1P matrix); WT2l|WT2r|WTg contiguous.
  bf16*     WT1l = (bf16*)    take((size_t)HID * K1P * 2);
  bf16*     WT1r = (bf16*)    take((size_t)HID * K1P * 2);
  bf16*     WT2l = (bf16*)    take((size_t)HID * HID * 2);
  bf16*     WT2r = (bf16*)    take((size_t)HID * HID * 2);
  bf16*     WTg  = (bf16*)    take((size_t)HID * HID * 2);
  bf16*     AT1P = (bf16*)    take((size_t)(HID / 32) * 512 * 2);
  bf16*     AT2P = (bf16*)    take((size_t)(HID / 32) * 512 * 2);
  float*    LOG  = (float*)   take((size_t)E_TOT * 16 * 4);
  int*      DEGI = (int*)     take((size_t)N_NODES * 4);
  int*      ROWP = (int*)     take((size_t)(N_NODES + 1) * 4);
  int*      CURS = (int*)     take((size_t)N_NODES * 4);
  int*      SRCG = (int*)     take((size_t)N_EDGES * 4);
  int*      DSTG = (int*)     take((size_t)N_EDGES * 4);
  float*    DINV = (float*)   take((size_t)N_NODES * 4);
  int*      GST  = (int*)     take((size_t)(N_GRAPHS + 1) * 4);
  int*      BSUM = (int*)     take((size_t)SCB * 4);

  dim3 blk(256);
  auto fill = [&](void* p, unsigned v, int n){
    fill_u32<<<dim3((n + 255) / 256), blk, 0, stream>>>((unsigned*)p, v, n);
  };
  const int MB8     = ((N_NODES + BM - 1) / BM + 7) / 8;   // row strips per XCD (49)
  const int nblocks = (N_NODES * 64 + 255) / 256;
  const int lblocks = (N_TILES * 64 + 255) / 256;
  const int reblk   = (N_EDGES + 255) / 256;
  const int apn     = (HID / 32) * 512;

  // ---- prep + CSR ----
  conv_x<<<(N_NODES * K1P + 255) / 256, blk, 0, stream>>>(x, XB);
  conv_wT2<<<(2 * HID * K1P + 255) / 256, blk, 0, stream>>>(Wl1, Wr1, WT1l, IN_DIM, HID, K1P);
  conv_wT3t<<<dim3(HID / 32, HID / 32, 3), blk, 0, stream>>>(Wl2, Wr2, Wg, WT2l);
  conv_attP<<<(apn + 255) / 256, blk, 0, stream>>>(a1, AT1P, HEADS);
  conv_attP<<<(apn + 255) / 256, blk, 0, stream>>>(a2, AT2P, 1);
  fill(DEGI, 0u, N_NODES);
  count_deg<<<reblk, blk, 0, stream>>>(edst, DEGI);
  scan_blk<<<dim3(SCB), blk, 0, stream>>>(DEGI, ROWP, DINV, BSUM);
  scan_top<<<dim3(1), blk, 0, stream>>>(BSUM, ROWP);
  scan_add<<<dim3(SCB), blk, 0, stream>>>(BSUM, ROWP, CURS);
  bucket_edges<<<reblk, blk, 0, stream>>>(esrc, edst, CURS, SRCG, DSTG);
  graph_bounds<<<(N_NODES + 255) / 256, blk, 0, stream>>>(batch, GST);

  // ---- GATv2 layer 1 (merged Wl|Wr GEMM, N=1280) ----
  mfma_gemm<<<dim3(8 * MB8 * 10), blk, 0, stream>>>(XB, WT1l, X1, X2, N_NODES, K1P, 10);
  logits_mfma<<<lblocks, blk, 0, stream>>>(X1, X2, SRCG, DSTG, AT1P, LOG, 0);
  gat1_agg<<<nblocks, blk, 0, stream>>>(X1, SRCG, ROWP, LOG, b1, H);

  // ---- GATv2 layer 2 (merged Wl|Wr GEMM, N=1280; compact logits) ----
  mfma_gemm<<<dim3(8 * MB8 * 10), blk, 0, stream>>>(H, WT2l, X1, X2, N_NODES, HID, 10);
  logits_mfma<<<lblocks, blk, 0, stream>>>(X1, X2, SRCG, DSTG, AT2P, LOG, 1);
  gat2_agg<<<nblocks, blk, 0, stream>>>(X1, SRCG, ROWP, LOG, b2, H);

  // ---- GCN + pooling ----
  mfma_gemm<<<dim3(8 * MB8 * 5), blk, 0, stream>>>(H, WTg, X1, X1, N_NODES, HID, 5);
  gcn_gather<<<nblocks, blk, 0, stream>>>(X1, SRCG, ROWP, DINV, bg, X2);
  pool_graph<<<dim3(N_GRAPHS), dim3(640), 0, stream>>>(X2, GST, (float*)d_out);
}